// Round 6
// baseline (898.794 us; speedup 1.0000x reference)
//
#include <hip/hip_runtime.h>
#include <hip/hip_bf16.h>

// ---------------------------------------------------------------------------
// Transformer_Light forward on MI355X (gfx950).
// I/O dtype: float32 buffers; internal bf16 MFMA with f32 accumulation.
//
// Output layout (f32 elements in d_out):
//   [0..511]        match_scores (8,64)
//   [512]           match_loss
//   [513..656]      cls_scores (8,18)
//   [657]           cls_loss
//   [658..30766833] dc_scores (8,2,63,30522)
//   [30766834]      dc_loss
// ---------------------------------------------------------------------------

typedef __hip_bfloat16 bf16;
typedef __attribute__((ext_vector_type(8))) __bf16 bf16x8;
typedef __attribute__((ext_vector_type(4))) float floatx4;

#define NB 8
#define NP 64
#define NT 63
#define NK 2
#define ND 512
#define NDFF 2048
#define NV 30522
#define NNC 18
#define NS 127
#define NSEQ 24
#define NROWS (NSEQ*NS)   // 3048

#define OUT_MS 0
#define OUT_MLOSS 512
#define OUT_CS 513
#define OUT_CLOSS 657
#define OUT_DC 658
#define OUT_DCLOSS 30766834

#define C2M 1008
#define C2N 30522
#define C2K 768
#define C2NT 239   // ceil(30522/128)
#define C2H  478   // 64-col partial windows per row (2 per 128-col tile)

__device__ __forceinline__ float bflo(unsigned u){ return __uint_as_float(u << 16); }
__device__ __forceinline__ float bfhi(unsigned u){ return __uint_as_float(u & 0xffff0000u); }

// async global->LDS, 16B per lane. LDS dest must be wave-uniform base + lane*16.
__device__ __forceinline__ void gload16(const void* g, void* l) {
    __builtin_amdgcn_global_load_lds(
        (const __attribute__((address_space(1))) unsigned*)g,
        (__attribute__((address_space(3))) unsigned*)l, 16, 0, 0);
}

// ---------------------------------------------------------------------------
// 64x64-tile GEMM: global_load_lds width-16 staging (m97 pattern), 4 waves
// of 32x32 output, 2x2 acc of 16x16x32 MFMA. bf16 out, bias/resid/relu.
// (r5-verified)
// ---------------------------------------------------------------------------
__global__ __launch_bounds__(256) void gemm_kernel(
    const bf16* __restrict__ A, const bf16* __restrict__ WT,
    const float* __restrict__ bias, const bf16* __restrict__ resid,
    bf16* __restrict__ C, int M, int N, int K, int relu)
{
    __shared__ bf16 As[64 * 32];
    __shared__ bf16 Bs[64 * 32];
    const int tid = threadIdx.x;
    const int m0 = blockIdx.x * 64;
    const int n0 = blockIdx.y * 64;
    const int lane = tid & 63;
    const int wave = tid >> 6;
    const int wm = (wave >> 1) * 32, wn = (wave & 1) * 32;
    const int quad = lane >> 4, r = lane & 15;
    // staging: thread covers granule (tid&3) of row (tid>>2); LDS linear.
    const int srow = tid >> 2;
    const int sk = (tid & 3) * 8;
    const int ar = min(m0 + srow, M - 1);
    const int br = min(n0 + srow, N - 1);
    bf16* lA = As + tid * 8;   // == srow*32 + sk ; wave-uniform base + lane*16B
    bf16* lB = Bs + tid * 8;

    floatx4 acc[2][2] = {};

    for (int k0 = 0; k0 < K; k0 += 32) {
        __syncthreads();
        gload16(A  + (size_t)ar * K + k0 + sk, lA);
        gload16(WT + (size_t)br * K + k0 + sk, lB);
        __syncthreads();

        bf16x8 a0 = *(const bf16x8*)(&As[(wm + r)      * 32 + quad * 8]);
        bf16x8 a1 = *(const bf16x8*)(&As[(wm + 16 + r) * 32 + quad * 8]);
        bf16x8 b0 = *(const bf16x8*)(&Bs[(wn + r)      * 32 + quad * 8]);
        bf16x8 b1 = *(const bf16x8*)(&Bs[(wn + 16 + r) * 32 + quad * 8]);
        acc[0][0] = __builtin_amdgcn_mfma_f32_16x16x32_bf16(a0, b0, acc[0][0], 0, 0, 0);
        acc[0][1] = __builtin_amdgcn_mfma_f32_16x16x32_bf16(a0, b1, acc[0][1], 0, 0, 0);
        acc[1][0] = __builtin_amdgcn_mfma_f32_16x16x32_bf16(a1, b0, acc[1][0], 0, 0, 0);
        acc[1][1] = __builtin_amdgcn_mfma_f32_16x16x32_bf16(a1, b1, acc[1][1], 0, 0, 0);
    }

    #pragma unroll
    for (int ti = 0; ti < 2; ++ti)
    #pragma unroll
    for (int tj = 0; tj < 2; ++tj) {
        int col = n0 + wn + tj * 16 + r;
        if (col >= N) continue;
        float bvv = bias ? bias[col] : 0.f;
        #pragma unroll
        for (int rr = 0; rr < 4; ++rr) {
            int row = m0 + wm + ti * 16 + quad * 4 + rr;
            if (row >= M) continue;
            float v = acc[ti][tj][rr] + bvv;
            if (resid) v += (float)resid[(size_t)row * N + col];
            if (relu)  v = v > 0.f ? v : 0.f;
            C[(size_t)row * N + col] = __float2bfloat16(v);
        }
    }
}

// ---------------------------------------------------------------------------
// 128x128-tile GEMM, m97-style: global_load_lds staging, 4 waves x (64x64),
// 4x4 acc of 16x16x32 MFMA. bf16 out, bias/resid/relu.
// (weights are L2-resident here -> dbuf not needed per m99/m100)
// ---------------------------------------------------------------------------
__global__ __launch_bounds__(256) void gemm128_kernel(
    const bf16* __restrict__ A, const bf16* __restrict__ WT,
    const float* __restrict__ bias, const bf16* __restrict__ resid,
    bf16* __restrict__ C, int M, int N, int K, int relu)
{
    __shared__ bf16 As[128 * 32];
    __shared__ bf16 Bs[128 * 32];
    const int tid = threadIdx.x;
    const int m0 = blockIdx.x * 128;
    const int n0 = blockIdx.y * 128;
    const int lane = tid & 63, wave = tid >> 6;
    const int quad = lane >> 4, r = lane & 15;
    const int wm = (wave >> 1) * 64, wn = (wave & 1) * 64;
    const int srow0 = wave * 32 + (lane >> 2);
    const int srow1 = srow0 + 16;
    const int sk = (lane & 3) * 8;
    const int ar0 = min(m0 + srow0, M - 1), ar1 = min(m0 + srow1, M - 1);
    const int br0 = min(n0 + srow0, N - 1), br1 = min(n0 + srow1, N - 1);
    bf16* lA = As + srow0 * 32 + sk;
    bf16* lB = Bs + srow0 * 32 + sk;

    floatx4 acc[4][4] = {};

    for (int k0 = 0; k0 < K; k0 += 32) {
        __syncthreads();
        gload16(A  + (size_t)ar0 * K + k0 + sk, lA);
        gload16(A  + (size_t)ar1 * K + k0 + sk, lA + 512);
        gload16(WT + (size_t)br0 * K + k0 + sk, lB);
        gload16(WT + (size_t)br1 * K + k0 + sk, lB + 512);
        __syncthreads();

        bf16x8 a[4], b[4];
        #pragma unroll
        for (int ti = 0; ti < 4; ++ti)
            a[ti] = *(const bf16x8*)(&As[(wm + ti * 16 + r) * 32 + quad * 8]);
        #pragma unroll
        for (int tj = 0; tj < 4; ++tj)
            b[tj] = *(const bf16x8*)(&Bs[(wn + tj * 16 + r) * 32 + quad * 8]);
        #pragma unroll
        for (int ti = 0; ti < 4; ++ti)
            #pragma unroll
            for (int tj = 0; tj < 4; ++tj)
                acc[ti][tj] = __builtin_amdgcn_mfma_f32_16x16x32_bf16(a[ti], b[tj], acc[ti][tj], 0, 0, 0);
    }

    #pragma unroll
    for (int ti = 0; ti < 4; ++ti)
    #pragma unroll
    for (int tj = 0; tj < 4; ++tj) {
        int col = n0 + wn + tj * 16 + r;
        if (col >= N) continue;
        float bvv = bias ? bias[col] : 0.f;
        #pragma unroll
        for (int rr = 0; rr < 4; ++rr) {
            int row = m0 + wm + ti * 16 + quad * 4 + rr;
            if (row >= M) continue;
            float v = acc[ti][tj][rr] + bvv;
            if (resid) v += (float)resid[(size_t)row * N + col];
            if (relu)  v = v > 0.f ? v : 0.f;
            C[(size_t)row * N + col] = __float2bfloat16(v);
        }
    }
}

// ---------------------------------------------------------------------------
// cap2 GEMM specialized: C[1008,30522] = A[1008,768] @ WT[30522,768]^T + bias.
// XCD swizzle + register-direct f32 epilogue (r1-verified) + minimum 2-phase
// double-buffer: issue tile t+1's global_load_lds BEFORE computing tile t,
// ONE __syncthreads per K-step (vs 2). WT streams 47MB from HBM (~900cy
// latency, not L2-fit) -> prefetch-under-compute has real headroom here,
// unlike the L2-resident m99/m100 case where dbuf was neutral.
// ---------------------------------------------------------------------------
__global__ __launch_bounds__(256) void gemm_cap2_kernel(
    const bf16* __restrict__ A, const bf16* __restrict__ WT,
    const float* __restrict__ bias, float* __restrict__ Cf,
    float2* __restrict__ part)
{
    __shared__ bf16 As[2][128 * 32];
    __shared__ bf16 Bs[2][128 * 32];
    const int id = blockIdx.x;
    const int xcd = id & 7, q = id >> 3;
    const int mt = q & 7, cg = q >> 3;
    const int nt = cg * 8 + xcd;
    if (nt >= C2NT) return;
    const int m0 = mt * 128, n0 = nt * 128;

    const int tid = threadIdx.x;
    const int lane = tid & 63, wave = tid >> 6;
    const int quad = lane >> 4, r = lane & 15;
    const int wm = (wave >> 1) * 64, wn = (wave & 1) * 64;
    const int srow0 = wave * 32 + (lane >> 2);
    const int sk = (lane & 3) * 8;
    const int ar0 = min(m0 + srow0,      C2M - 1), ar1 = min(m0 + srow0 + 16, C2M - 1);
    const int br0 = min(n0 + srow0,      C2N - 1), br1 = min(n0 + srow0 + 16, C2N - 1);
    const bf16* aR0 = A  + (size_t)ar0 * C2K + sk;
    const bf16* aR1 = A  + (size_t)ar1 * C2K + sk;
    const bf16* bR0 = WT + (size_t)br0 * C2K + sk;
    const bf16* bR1 = WT + (size_t)br1 * C2K + sk;
    const int soff = srow0 * 32 + sk;   // elem offset inside one buffer

    floatx4 acc[4][4] = {};

    // prologue: stage K-tile 0 into buffer 0
    gload16(aR0, &As[0][soff]);
    gload16(aR1, &As[0][soff + 512]);
    gload16(bR0, &Bs[0][soff]);
    gload16(bR1, &Bs[0][soff + 512]);
    __syncthreads();   // vmcnt(0): buf0 ready

    int cur = 0;
    #pragma unroll 1
    for (int t = 0; t < 24; ++t) {
        // issue next tile's loads into the other buffer (async, in flight
        // across the compute below; drained by the __syncthreads at bottom)
        if (t + 1 < 24) {
            const int k1 = (t + 1) * 32;
            gload16(aR0 + k1, &As[cur ^ 1][soff]);
            gload16(aR1 + k1, &As[cur ^ 1][soff + 512]);
            gload16(bR0 + k1, &Bs[cur ^ 1][soff]);
            gload16(bR1 + k1, &Bs[cur ^ 1][soff + 512]);
        }
        // compute current tile
        bf16x8 a[4], b[4];
        #pragma unroll
        for (int ti = 0; ti < 4; ++ti)
            a[ti] = *(const bf16x8*)(&As[cur][(wm + ti * 16 + r) * 32 + quad * 8]);
        #pragma unroll
        for (int tj = 0; tj < 4; ++tj)
            b[tj] = *(const bf16x8*)(&Bs[cur][(wn + tj * 16 + r) * 32 + quad * 8]);
        #pragma unroll
        for (int ti = 0; ti < 4; ++ti)
            #pragma unroll
            for (int tj = 0; tj < 4; ++tj)
                acc[ti][tj] = __builtin_amdgcn_mfma_f32_16x16x32_bf16(a[ti], b[tj], acc[ti][tj], 0, 0, 0);
        // one barrier per K-step: drains next-tile loads (vmcnt) and this
        // tile's ds_reads (lgkm) so the buffer can be overwritten next iter.
        __syncthreads();
        cur ^= 1;
    }

    // ---- register-direct epilogue (unchanged, r1-verified) ----
    float bv[4];
    bool cok[4];
    #pragma unroll
    for (int tj = 0; tj < 4; ++tj) {
        int col = n0 + wn + tj * 16 + r;
        cok[tj] = (col < C2N);
        bv[tj] = cok[tj] ? bias[col] : 0.f;
    }
    const int half = (wn >> 6);   // 0 or 1: which 64-col tile of this 128-tile

    #pragma unroll
    for (int ti = 0; ti < 4; ++ti) {
        #pragma unroll
        for (int rr = 0; rr < 4; ++rr) {
            const int rowg = m0 + wm + ti * 16 + quad * 4 + rr;
            const bool rok = (rowg < C2M);
            float v[4], vp[4];
            #pragma unroll
            for (int tj = 0; tj < 4; ++tj) {
                v[tj]  = acc[ti][tj][rr] + bv[tj];
                vp[tj] = cok[tj] ? v[tj] : -1e30f;
            }
            if (rok) {
                float* orow = Cf + (size_t)rowg * C2N;
                #pragma unroll
                for (int tj = 0; tj < 4; ++tj)
                    if (cok[tj]) orow[n0 + wn + tj * 16 + r] = v[tj];
            }
            float mx = fmaxf(fmaxf(vp[0], vp[1]), fmaxf(vp[2], vp[3]));
            #pragma unroll
            for (int o = 1; o < 16; o <<= 1) mx = fmaxf(mx, __shfl_xor(mx, o));
            float s = 0.f;
            #pragma unroll
            for (int tj = 0; tj < 4; ++tj)
                if (cok[tj]) s += __expf(v[tj] - mx);
            #pragma unroll
            for (int o = 1; o < 16; o <<= 1) s += __shfl_xor(s, o);
            if (r == 0 && rok)
                part[(size_t)rowg * C2H + nt * 2 + half] = make_float2(mx, s);
        }
    }
}

// ---------------------------------------------------------------------------
// Batched weight prep: transposes (f32 KxN -> bf16 NxK) + f32->bf16 copies.
// ---------------------------------------------------------------------------
struct PrepDesc { const float* src; bf16* dst; int K, N, tx, start, kind; };
struct PrepArgs { PrepDesc d[14]; };

__global__ __launch_bounds__(256) void prep_kernel(PrepArgs pa)
{
    const int bid = blockIdx.x;
    int op = 0;
    #pragma unroll
    for (int i = 1; i < 14; ++i) if (bid >= pa.d[i].start) op = i;
    const PrepDesc D = pa.d[op];
    const int lt = bid - D.start;
    const int tid = threadIdx.x;
    if (D.kind == 1) {   // contiguous f32 -> bf16 (sizes are exact *1024)
        int base = lt * 1024 + tid * 4;
        float4 v = *(const float4*)(D.src + base);
        bf16 o[4] = { __float2bfloat16(v.x), __float2bfloat16(v.y),
                      __float2bfloat16(v.z), __float2bfloat16(v.w) };
        *(uint2*)(D.dst + base) = *(uint2*)o;
    } else {             // 32x32 transpose tile (dims exact multiples of 32)
        __shared__ float tile[32][33];
        const int tx = tid & 31, ty = tid >> 5;
        const int n0 = (lt % D.tx) * 32, k0 = (lt / D.tx) * 32;
        #pragma unroll
        for (int yy = 0; yy < 32; yy += 8)
            tile[ty + yy][tx] = D.src[(size_t)(k0 + ty + yy) * D.N + n0 + tx];
        __syncthreads();
        #pragma unroll
        for (int yy = 0; yy < 32; yy += 8)
            D.dst[(size_t)(n0 + ty + yy) * D.K + k0 + tx] =
                __float2bfloat16(tile[tx][ty + yy]);
    }
}

// big standalone transpose for cap_w2 (runs late, overlays encoder arena)
__global__ __launch_bounds__(256) void transpose_kernel(
    const float* __restrict__ src, bf16* __restrict__ dst, int K, int N)
{
    __shared__ float tile[32][33];
    const int tx = threadIdx.x & 31, ty = threadIdx.x >> 5;
    const int n0 = blockIdx.x * 32, k0 = blockIdx.y * 32;
    #pragma unroll
    for (int yy = 0; yy < 32; yy += 8) {
        int k = k0 + ty + yy, n = n0 + tx;
        if (k < K && n < N) tile[ty + yy][tx] = src[(size_t)k * N + n];
    }
    __syncthreads();
    #pragma unroll
    for (int yy = 0; yy < 32; yy += 8) {
        int n = n0 + ty + yy, k = k0 + tx;
        if (n < N && k < K) dst[(size_t)n * K + k] = __float2bfloat16(tile[tx][ty + yy]);
    }
}

// ---------------------------------------------------------------------------
__global__ __launch_bounds__(256) void box_mean_kernel(
    const bf16* __restrict__ box, float* __restrict__ bm)
{
    const int b = blockIdx.x, tid = threadIdx.x;
    float s0 = 0.f, s1 = 0.f;
    for (int p = 0; p < NP; ++p) {
        const bf16* rw = box + (size_t)(b * NP + p) * ND;
        s0 += (float)rw[tid];
        s1 += (float)rw[tid + 256];
    }
    bm[b * ND + tid]       = s0 * (1.f / 64.f);
    bm[b * ND + tid + 256] = s1 * (1.f / 64.f);
}

__global__ __launch_bounds__(256) void build_x_kernel(
    const bf16* __restrict__ box, const bf16* __restrict__ txt,
    const float* __restrict__ bm, const int* __restrict__ tp,
    bf16* __restrict__ X)
{
    int idx = blockIdx.x * 256 + threadIdx.x;
    if (idx >= NROWS * ND) return;
    int d = idx & (ND - 1);
    int rs = idx >> 9;
    int row = rs % NS, seq = rs / NS;
    float v;
    if (seq < NB) {
        int b = seq;
        if (row < NP) v = (float)box[(size_t)(b * NP + row) * ND + d];
        else v = (float)txt[(size_t)(b * NT + row - NP) * ND + d] + bm[b * ND + d];
    } else {
        int s2 = seq - NB, b = s2 >> 1, k = s2 & 1;
        if (row < NP) v = (float)box[(size_t)(b * NP + row) * ND + d];
        else v = (float)txt[(size_t)(b * NT + row - NP) * ND + d]
               + (float)box[(size_t)(b * NP + tp[b * NK + k]) * ND + d];
    }
    X[idx] = __float2bfloat16(v);
}

// ---------------------------------------------------------------------------
__global__ __launch_bounds__(256) void attn_kernel(
    const bf16* __restrict__ QKV, bf16* __restrict__ Aout)
{
    const int blk = blockIdx.x;
    const int seq = blk / NS, i = blk % NS;
    const int tid = threadIdx.x;
    __shared__ float qs[ND];
    __shared__ float sc[128];
    __shared__ float red[64];

    const bf16* qrow = QKV + (size_t)(seq * NS + i) * 1536;
    qs[tid]       = (float)qrow[tid];
    qs[tid + 256] = (float)qrow[tid + 256];
    __syncthreads();

    int jmax = (seq < NB) ? NS : ((i < NP) ? NP : (i + 1));

    if (tid < NS) {
        const uint4* kp = (const uint4*)(QKV + (size_t)(seq * NS + tid) * 1536 + ND);
        float d = 0.f;
        #pragma unroll 4
        for (int c = 0; c < 64; ++c) {
            uint4 u = kp[c];
            int b0 = c * 8;
            d += qs[b0+0]*bflo(u.x) + qs[b0+1]*bfhi(u.x)
               + qs[b0+2]*bflo(u.y) + qs[b0+3]*bfhi(u.y)
               + qs[b0+4]*bflo(u.z) + qs[b0+5]*bfhi(u.z)
               + qs[b0+6]*bflo(u.w) + qs[b0+7]*bfhi(u.w);
        }
        sc[tid] = (tid < jmax) ? d * 0.04419417382415922f : -1e9f;
    } else if (tid == NS) {
        sc[NS] = -1e9f;
    }
    __syncthreads();

    if (tid < 64) red[tid] = fmaxf(sc[tid], sc[tid + 64]);
    __syncthreads();
    for (int s = 32; s > 0; s >>= 1) {
        if (tid < s) red[tid] = fmaxf(red[tid], red[tid + s]);
        __syncthreads();
    }
    float m = red[0];
    __syncthreads();

    if (tid < 128) sc[tid] = __expf(sc[tid] - m);
    __syncthreads();
    if (tid < 64) red[tid] = sc[tid] + sc[tid + 64];
    __syncthreads();
    for (int s = 32; s > 0; s >>= 1) {
        if (tid < s) red[tid] += red[tid + s];
        __syncthreads();
    }
    float inv = 1.f / red[0];

    const unsigned* vp = (const unsigned*)(QKV + (size_t)(seq * NS) * 1536 + 1024);
    float a0 = 0.f, a1 = 0.f;
    for (int j = 0; j < jmax; ++j) {
        float p = sc[j];
        unsigned u = vp[(size_t)j * 768 + tid];
        a0 += p * bflo(u);
        a1 += p * bfhi(u);
    }
    bf16* orow = Aout + (size_t)(seq * NS + i) * ND;
    orow[2 * tid]     = __float2bfloat16(a0 * inv);
    orow[2 * tid + 1] = __float2bfloat16(a1 * inv);
}

// ---------------------------------------------------------------------------
__global__ __launch_bounds__(256) void ln_kernel(
    const bf16* __restrict__ Y, const float* __restrict__ g,
    const float* __restrict__ b, bf16* __restrict__ X)
{
    const int row = blockIdx.x, tid = threadIdx.x;
    const bf16* y = Y + (size_t)row * ND;
    float v0 = (float)y[tid], v1 = (float)y[tid + 256];
    __shared__ float rs[256], rq[256];
    rs[tid] = v0 + v1;
    rq[tid] = v0 * v0 + v1 * v1;
    __syncthreads();
    for (int s = 128; s > 0; s >>= 1) {
        if (tid < s) { rs[tid] += rs[tid + s]; rq[tid] += rq[tid + s]; }
        __syncthreads();
    }
    float mean = rs[0] * (1.f / ND);
    float var = rq[0] * (1.f / ND) - mean * mean;
    float rstd = rsqrtf(var + 1e-5f);
    bf16* x = X + (size_t)row * ND;
    x[tid]       = __float2bfloat16((v0 - mean) * rstd * g[tid] + b[tid]);
    x[tid + 256] = __float2bfloat16((v1 - mean) * rstd * g[tid + 256] + b[tid + 256]);
}

// ---------------------------------------------------------------------------
__global__ __launch_bounds__(256) void match_head_kernel(
    const bf16* __restrict__ X, const float* __restrict__ w1, const float* __restrict__ b1,
    const float* __restrict__ w2, const float* __restrict__ b2,
    float* __restrict__ msf, float* __restrict__ out)
{
    const int blk = blockIdx.x;
    const int b = blk >> 6, p = blk & 63;
    const int tid = threadIdx.x;
    const bf16* x = X + (size_t)(b * NS + p) * ND;
    __shared__ float xs[ND];
    __shared__ float red[256];
    xs[tid] = (float)x[tid]; xs[tid + 256] = (float)x[tid + 256];
    __syncthreads();
    float h = b1[tid];
    for (int d = 0; d < ND; ++d) h += xs[d] * w1[d * 256 + tid];
    red[tid] = h * w2[tid];
    __syncthreads();
    for (int s = 128; s > 0; s >>= 1) {
        if (tid < s) red[tid] += red[tid + s];
        __syncthreads();
    }
    if (tid == 0) {
        float scv = red[0] + b2[0];
        msf[blk] = scv;
        out[OUT_MS + blk] = scv;
    }
}

__global__ __launch_bounds__(256) void cls_head_kernel(
    const bf16* __restrict__ X, const float* __restrict__ w1, const float* __restrict__ b1,
    const float* __restrict__ w2, const float* __restrict__ b2,
    float* __restrict__ csf, float* __restrict__ out)
{
    const int b = blockIdx.x, tid = threadIdx.x;
    const bf16* x = X + (size_t)(b * NS + NP) * ND;
    __shared__ float xs[ND];
    __shared__ float hs[256];
    xs[tid] = (float)x[tid]; xs[tid + 256] = (float)x[tid + 256];
    __syncthreads();
    float h = b1[tid];
    for (int d = 0; d < ND; ++d) h += xs[d] * w1[d * 256 + tid];
    hs[tid] = h;
    __syncthreads();
    if (tid < NNC) {
        float scv = b2[tid];
        for (int c = 0; c < 256; ++c) scv += hs[c] * w2[c * NNC + tid];
        csf[b * NNC + tid] = scv;
        out[OUT_CS + b * NNC + tid] = scv;
    }
}

__global__ void small_loss_kernel(
    const float* __restrict__ msf, const float* __restrict__ csf,
    const int* __restrict__ tp, const int* __restrict__ tc, float* __restrict__ out)
{
    const int tid = threadIdx.x;
    float mloss = 0.f;
    for (int b = 0; b < NB; ++b) {
        float s = msf[b * NP + tid];
        float m = s;
        for (int o = 32; o > 0; o >>= 1) m = fmaxf(m, __shfl_xor(m, o));
        float e = __expf(s - m);
        float sum = e;
        for (int o = 32; o > 0; o >>= 1) sum += __shfl_xor(sum, o);
        float lse = m + __logf(sum);
        float w = (tid == tp[2 * b] || tid == tp[2 * b + 1]) ? 0.5f : 0.f;
        float c = w * (lse - s);
        for (int o = 32; o > 0; o >>= 1) c += __shfl_xor(c, o);
        mloss += c;
    }
    float closs = 0.f;
    for (int b = 0; b < NB; ++b) {
        float s = (tid < NNC) ? csf[b * NNC + tid] : -1e30f;
        float m = s;
        for (int o = 32; o > 0; o >>= 1) m = fmaxf(m, __shfl_xor(m, o));
        float e = (tid < NNC) ? __expf(s - m) : 0.f;
        float sum = e;
        for (int o = 32; o > 0; o >>= 1) sum += __shfl_xor(sum, o);
        if (tid == 0) closs += (m + __logf(sum)) - csf[b * NNC + tc[b]];
    }
    if (tid == 0) {
        out[OUT_MLOSS] = mloss * (1.f / NB);
        out[OUT_CLOSS] = closs * (1.f / NB);
    }
}

__global__ __launch_bounds__(256) void gather_xc_kernel(
    const bf16* __restrict__ X, bf16* __restrict__ Xc)
{
    int idx = blockIdx.x * 256 + threadIdx.x;
    if (idx >= 1008 * ND) return;
    int d = idx & (ND - 1);
    int r = idx >> 9;
    int seq = NB + r / NT, t = r % NT;
    Xc[idx] = X[(size_t)(seq * NS + NP + t) * ND + d];
}

// combine per-tile softmax partials -> dc loss (two passes over L2-resident part)
__global__ void dc_combine_kernel(
    const float2* __restrict__ part, const float* __restrict__ scores,
    const int* __restrict__ twid, float* __restrict__ accf)
{
    const int rr = blockIdx.x, t = threadIdx.x;
    const float2* pr = part + (size_t)rr * C2H;
    float mx = -1e30f;
    for (int i = t; i < C2H; i += 64) mx = fmaxf(mx, pr[i].x);
    for (int o = 1; o < 64; o <<= 1) mx = fmaxf(mx, __shfl_xor(mx, o));
    float s = 0.f;
    for (int i = t; i < C2H; i += 64) {
        float2 p = pr[i];
        s += p.y * __expf(p.x - mx);
    }
    for (int o = 1; o < 64; o <<= 1) s += __shfl_xor(s, o);
    if (t == 0) {
        int b = rr / 126, rem = rr % 126, tok = rem % 63;
        int wid = twid[b * 64 + 1 + tok];
        float lse = mx + __logf(s);
        atomicAdd(accf, (lse - scores[(size_t)rr * C2N + wid]) * (1.f / 504.f));
    }
}

__global__ void init_kernel(float* __restrict__ acc)
{
    if (threadIdx.x < 16) acc[threadIdx.x] = 0.f;
}

__global__ void finalize_kernel(const float* __restrict__ acc, float* __restrict__ out)
{
    out[OUT_DCLOSS] = acc[0];
}

// ---------------------------------------------------------------------------
extern "C" void kernel_launch(void* const* d_in, const int* in_sizes, int n_in,
                              void* d_out, int out_size, void* d_ws, size_t ws_size,
                              hipStream_t stream)
{
    const float* instances = (const float*)d_in[0];
    const float* text_emb  = (const float*)d_in[1];
    const int*   tp        = (const int*)d_in[2];
    const int*   twid      = (const int*)d_in[3];
    const int*   tcls      = (const int*)d_in[4];
    const float* Wi1 = (const float*)d_in[5];  const float* bi1 = (const float*)d_in[6];
    const float* Wi2 = (const float*)d_in[7];  const float* bi2 = (const float*)d_in[8];
    const float* Ww  = (const float*)d_in[9];  const float* bw  = (const float*)d_in[10];
    const float* qkv_w = (const float*)d_in[11]; const float* qkv_b = (const float*)d_in[12];
    const float* out_w = (const float*)d_in[13]; const float* out_b = (const float*)d_in[14];
    const float* ln1_g = (const float*)d_in[15]; const float* ln1_b = (const float*)d_in[16];
    const float* ff1_w = (const float*)d_in[17]; const float* ff1_b = (const float*)d_in[18];
    const float* ff2_w = (const float*)d_in[19]; const float* ff2_b = (const float*)d_in[20];
    const float* ln2_g = (const float*)d_in[21]; const float* ln2_b = (const float*)d_in[22];
    const float* grd_w1 = (const float*)d_in[23]; const float* grd_b1 = (const float*)d_in[24];
    const float* grd_w2 = (const float*)d_in[25]; const float* grd_b2 = (const float*)d_in[26];
    const float* cls_w1 = (const float*)d_in[27]; const float* cls_b1 = (const float*)d_in[28];
    const float* cls_w2 = (const float*)d_in[29]; const float* cls_b2 = (const float*)d_in[30];
    const float* cap_w1 = (const float*)d_in[31]; const float* cap_b1 = (const float*)d_in[32];
    const float* cap_w2 = (const float*)d_in[33]; const float* cap_b2 = (const float*)d_in[34];

    float* out = (float*)d_out;

    // ---- workspace layout (~60 MB peak; cap_w2^T overlays encoder arena) ----
    char* base = (char*)d_ws;
    size_t o = 0;
    auto nxtb = [&](size_t bytes) -> char* {
        char* p = base + o; o += (bytes + 255) & ~(size_t)255; return p;
    };
    float*  bm   = (float*)nxtb(NB * ND * 4);
    float*  msf  = (float*)nxtb(512 * 4);
    float*  csf  = (float*)nxtb(144 * 4);
    float*  accf = (float*)nxtb(64);
    float2* part = (float2*)nxtb((size_t)C2M * C2H * 8);
    bf16* wt_cap1 = (bf16*)nxtb((size_t)768 * 512 * 2);
    bf16* Xc    = (bf16*)nxtb((size_t)1008 * 512 * 2);
    bf16* C1    = (bf16*)nxtb((size_t)1008 * 768 * 2);
    size_t arena0 = o;
    bf16* wt_wi1  = (bf16*)nxtb((size_t)1024 * 1536 * 2);
    bf16* wt_wi2  = (bf16*)nxtb((size_t)512 * 1024 * 2);
    bf16* wt_ww   = (bf16*)nxtb((size_t)512 * 768 * 2);
    bf16* wt_qkv  = (bf16*)nxtb((size_t)2 * 1536 * 512 * 2);
    bf16* wt_out  = (bf16*)nxtb((size_t)2 * 512 * 512 * 2);
    bf16* wt_ff1  = (bf16*)nxtb((size_t)2 * 2048 * 512 * 2);
    bf16* wt_ff2  = (bf16*)nxtb((size_t)2 * 512 * 2048 * 2);
    bf16* inst_b  = (bf16*)nxtb((size_t)512 * 1536 * 2);
    bf16* txt_b   = (bf16*)nxtb((size_t)504 * 768 * 2);
    bf16* box_h   = (bf16*)nxtb((size_t)512 * 1024 * 2);
    bf16* box     = (bf16*)nxtb((size_t)512 * 512 * 2);
    bf16* txt     = (bf16*)nxtb((size_t)504 * 512 * 2);
    bf16* X       = (bf16*)nxtb((size_t)NROWS * ND * 2);
    bf16* QKV     = (bf16*)nxtb((size_t)NROWS * 1536 * 2);
    bf16* Aout    = (bf16*)nxtb((size_t)NROWS * ND * 2);
    bf16* Ybuf    = (bf16*)nxtb((size_t)NROWS * ND * 2);
    bf16* Hbuf    = (bf16*)nxtb((size_t)NROWS * NDFF * 2);
    bf16* wt_cap2 = (bf16*)(base + arena0);  // 46.9 MB, overlays arena late

    const dim3 tb(256);

    init_kernel<<<1, 64, 0, stream>>>(accf);

    // ---- batched weight prep (12 transposes + 2 copies, one launch) ----
    PrepArgs pa;
    int cur = 0, pi = 0;
    auto addT = [&](const float* s, bf16* d, int K, int N) {
        pa.d[pi] = PrepDesc{ s, d, K, N, N / 32, cur, 0 };
        cur += (N / 32) * (K / 32); pi++;
    };
    auto addC = [&](const float* s, bf16* d, int elems) {
        pa.d[pi] = PrepDesc{ s, d, 0, 0, 0, cur, 1 };
        cur += elems / 1024; pi++;
    };
    addT(Wi1, wt_wi1, 1536, 1024);
    addT(Wi2, wt_wi2, 1024, 512);
    addT(Ww,  wt_ww,  768,  512);
    for (int l = 0; l < 2; ++l) {
        addT(qkv_w + (size_t)l * 512 * 1536, wt_qkv + (size_t)l * 1536 * 512, 512, 1536);
        addT(out_w + (size_t)l * 512 * 512,  wt_out + (size_t)l * 512 * 512,  512, 512);
        addT(ff1_w + (size_t)l * 512 * 2048, wt_ff1 + (size_t)l * 2048 * 512, 512, 2048);
        addT(ff2_w + (size_t)l * 2048 * 512, wt_ff2 + (size_t)l * 512 * 2048, 2048, 512);
    }
    addT(cap_w1, wt_cap1, 512, 768);
    addC(instances, inst_b, 512 * 1536);
    addC(text_emb,  txt_b,  504 * 768);
    prep_kernel<<<cur, tb, 0, stream>>>(pa);

    auto G64 = [&](const bf16* A, const bf16* WT, const float* bias, const bf16* resid,
                   bf16* C, int M, int N, int K, int relu) {
        dim3 g((M + 63) / 64, (N + 63) / 64);
        gemm_kernel<<<g, tb, 0, stream>>>(A, WT, bias, resid, C, M, N, K, relu);
    };
    auto G128 = [&](const bf16* A, const bf16* WT, const float* bias, const bf16* resid,
                    bf16* C, int M, int N, int K, int relu) {
        dim3 g((M + 127) / 128, (N + 127) / 128);
        gemm128_kernel<<<g, tb, 0, stream>>>(A, WT, bias, resid, C, M, N, K, relu);
    };

    // box/text embeddings
    G64(inst_b, wt_wi1, bi1, nullptr, box_h, 512, 1024, 1536, 0);
    G64(box_h,  wt_wi2, bi2, nullptr, box,   512, 512,  1024, 0);
    G64(txt_b,  wt_ww,  bw,  nullptr, txt,   504, 512,  768,  0);

    box_mean_kernel<<<NB, tb, 0, stream>>>(box, bm);
    build_x_kernel<<<(NROWS * ND) / 256, tb, 0, stream>>>(box, txt, bm, tp, X);

    // encoder, 2 layers
    for (int l = 0; l < 2; ++l) {
        G128(X, wt_qkv + (size_t)l * 1536 * 512, qkv_b + l * 1536, nullptr, QKV,
             NROWS, 1536, 512, 0);
        attn_kernel<<<NROWS, tb, 0, stream>>>(QKV, Aout);
        G64(Aout, wt_out + (size_t)l * 512 * 512, out_b + l * 512, X, Ybuf,
            NROWS, 512, 512, 0);
        ln_kernel<<<NROWS, tb, 0, stream>>>(Ybuf, ln1_g + l * 512, ln1_b + l * 512, X);
        G128(X, wt_ff1 + (size_t)l * 2048 * 512, ff1_b + l * 2048, nullptr, Hbuf,
             NROWS, 2048, 512, 1);
        G64(Hbuf, wt_ff2 + (size_t)l * 512 * 2048, ff2_b + l * 512, X, Ybuf,
            NROWS, 512, 2048, 0);
        ln_kernel<<<NROWS, tb, 0, stream>>>(Ybuf, ln2_g + l * 512, ln2_b + l * 512, X);
    }

    // heads + small losses
    match_head_kernel<<<512, tb, 0, stream>>>(X, grd_w1, grd_b1, grd_w2, grd_b2, msf, out);
    cls_head_kernel<<<NB, tb, 0, stream>>>(X, cls_w1, cls_b1, cls_w2, cls_b2, csf, out);
    small_loss_kernel<<<1, 64, 0, stream>>>(msf, csf, tp, tcls, out);

    gather_xc_kernel<<<(1008 * ND) / 256, tb, 0, stream>>>(X, Xc);
    G64(Xc, wt_cap1, cap_b1, nullptr, C1, 1008, 768, 512, 0);

    // caption vocab projection (f32 straight into d_out, fused softmax partials)
    {
        dim3 g((C2N + 31) / 32, (C2K + 31) / 32);
        transpose_kernel<<<g, tb, 0, stream>>>(cap_w2, wt_cap2, C2K, C2N);
    }
    gemm_cap2_kernel<<<8 * 8 * 30, tb, 0, stream>>>(C1, wt_cap2, cap_b2,
                                                    out + OUT_DC, part);

    dc_combine_kernel<<<1008, 64, 0, stream>>>(part, out + OUT_DC, twid, accf);
    finalize_kernel<<<1, 1, 0, stream>>>(accf, out);

    (void)in_sizes; (void)n_in; (void)out_size; (void)ws_size;
}

// Round 7
// 867.266 us; speedup vs baseline: 1.0364x; 1.0364x over previous
//
#include <hip/hip_runtime.h>
#include <hip/hip_bf16.h>

// ---------------------------------------------------------------------------
// Transformer_Light forward on MI355X (gfx950).
// I/O dtype: float32 buffers; internal bf16 MFMA with f32 accumulation.
//
// Output layout (f32 elements in d_out):
//   [0..511]        match_scores (8,64)
//   [512]           match_loss
//   [513..656]      cls_scores (8,18)
//   [657]           cls_loss
//   [658..30766833] dc_scores (8,2,63,30522)
//   [30766834]      dc_loss
// ---------------------------------------------------------------------------

typedef __hip_bfloat16 bf16;
typedef __attribute__((ext_vector_type(8))) __bf16 bf16x8;
typedef __attribute__((ext_vector_type(4))) float floatx4;

#define NB 8
#define NP 64
#define NT 63
#define NK 2
#define ND 512
#define NDFF 2048
#define NV 30522
#define NNC 18
#define NS 127
#define NSEQ 24
#define NROWS (NSEQ*NS)   // 3048

#define OUT_MS 0
#define OUT_MLOSS 512
#define OUT_CS 513
#define OUT_CLOSS 657
#define OUT_DC 658
#define OUT_DCLOSS 30766834

#define C2M 1008
#define C2N 30522
#define C2K 768
#define C2NT 239   // ceil(30522/128)
#define C2H  478   // 64-col partial windows per row (2 per 128-col tile)

__device__ __forceinline__ float bflo(unsigned u){ return __uint_as_float(u << 16); }
__device__ __forceinline__ float bfhi(unsigned u){ return __uint_as_float(u & 0xffff0000u); }

// async global->LDS, 16B per lane. LDS dest must be wave-uniform base + lane*16.
__device__ __forceinline__ void gload16(const void* g, void* l) {
    __builtin_amdgcn_global_load_lds(
        (const __attribute__((address_space(1))) unsigned*)g,
        (__attribute__((address_space(3))) unsigned*)l, 16, 0, 0);
}

// ---------------------------------------------------------------------------
// 64x64-tile GEMM, BK=64: global_load_lds width-16 staging into [2][64][32]
// (two 32-col K-sub-tiles -> fragment addressing identical to the verified
// BK=32 kernel per sub-tile), 8 MFMA per barrier pair (was 4 per 2 pairs).
// ---------------------------------------------------------------------------
__global__ __launch_bounds__(256) void gemm_kernel(
    const bf16* __restrict__ A, const bf16* __restrict__ WT,
    const float* __restrict__ bias, const bf16* __restrict__ resid,
    bf16* __restrict__ C, int M, int N, int K, int relu)
{
    __shared__ bf16 As[2][64 * 32];
    __shared__ bf16 Bs[2][64 * 32];
    const int tid = threadIdx.x;
    const int m0 = blockIdx.x * 64;
    const int n0 = blockIdx.y * 64;
    const int lane = tid & 63;
    const int wave = tid >> 6;
    const int wm = (wave >> 1) * 32, wn = (wave & 1) * 32;
    const int quad = lane >> 4, r = lane & 15;
    // staging: thread covers granule (tid&3) of row (tid>>2), both K-halves.
    const int srow = tid >> 2;
    const int sk = (tid & 3) * 8;
    const int ar = min(m0 + srow, M - 1);
    const int br = min(n0 + srow, N - 1);
    bf16* lA0 = &As[0][tid * 8];   // == srow*32 + sk ; wave-uniform + lane*16B
    bf16* lA1 = &As[1][tid * 8];
    bf16* lB0 = &Bs[0][tid * 8];
    bf16* lB1 = &Bs[1][tid * 8];

    floatx4 acc[2][2] = {};

    for (int k0 = 0; k0 < K; k0 += 64) {
        __syncthreads();
        gload16(A  + (size_t)ar * K + k0 + sk,      lA0);
        gload16(A  + (size_t)ar * K + k0 + 32 + sk, lA1);
        gload16(WT + (size_t)br * K + k0 + sk,      lB0);
        gload16(WT + (size_t)br * K + k0 + 32 + sk, lB1);
        __syncthreads();

        #pragma unroll
        for (int kh = 0; kh < 2; ++kh) {
            bf16x8 a0 = *(const bf16x8*)(&As[kh][(wm + r)      * 32 + quad * 8]);
            bf16x8 a1 = *(const bf16x8*)(&As[kh][(wm + 16 + r) * 32 + quad * 8]);
            bf16x8 b0 = *(const bf16x8*)(&Bs[kh][(wn + r)      * 32 + quad * 8]);
            bf16x8 b1 = *(const bf16x8*)(&Bs[kh][(wn + 16 + r) * 32 + quad * 8]);
            acc[0][0] = __builtin_amdgcn_mfma_f32_16x16x32_bf16(a0, b0, acc[0][0], 0, 0, 0);
            acc[0][1] = __builtin_amdgcn_mfma_f32_16x16x32_bf16(a0, b1, acc[0][1], 0, 0, 0);
            acc[1][0] = __builtin_amdgcn_mfma_f32_16x16x32_bf16(a1, b0, acc[1][0], 0, 0, 0);
            acc[1][1] = __builtin_amdgcn_mfma_f32_16x16x32_bf16(a1, b1, acc[1][1], 0, 0, 0);
        }
    }

    #pragma unroll
    for (int ti = 0; ti < 2; ++ti)
    #pragma unroll
    for (int tj = 0; tj < 2; ++tj) {
        int col = n0 + wn + tj * 16 + r;
        if (col >= N) continue;
        float bvv = bias ? bias[col] : 0.f;
        #pragma unroll
        for (int rr = 0; rr < 4; ++rr) {
            int row = m0 + wm + ti * 16 + quad * 4 + rr;
            if (row >= M) continue;
            float v = acc[ti][tj][rr] + bvv;
            if (resid) v += (float)resid[(size_t)row * N + col];
            if (relu)  v = v > 0.f ? v : 0.f;
            C[(size_t)row * N + col] = __float2bfloat16(v);
        }
    }
}

// ---------------------------------------------------------------------------
// 128x128-tile GEMM, BK=64 m97-style: [2][128][32] LDS, 32 MFMA per barrier
// pair. bf16 out, bias/resid/relu.
// ---------------------------------------------------------------------------
__global__ __launch_bounds__(256) void gemm128_kernel(
    const bf16* __restrict__ A, const bf16* __restrict__ WT,
    const float* __restrict__ bias, const bf16* __restrict__ resid,
    bf16* __restrict__ C, int M, int N, int K, int relu)
{
    __shared__ bf16 As[2][128 * 32];
    __shared__ bf16 Bs[2][128 * 32];
    const int tid = threadIdx.x;
    const int m0 = blockIdx.x * 128;
    const int n0 = blockIdx.y * 128;
    const int lane = tid & 63, wave = tid >> 6;
    const int quad = lane >> 4, r = lane & 15;
    const int wm = (wave >> 1) * 64, wn = (wave & 1) * 64;
    const int srow0 = wave * 32 + (lane >> 2);
    const int srow1 = srow0 + 16;
    const int sk = (lane & 3) * 8;
    const int ar0 = min(m0 + srow0, M - 1), ar1 = min(m0 + srow1, M - 1);
    const int br0 = min(n0 + srow0, N - 1), br1 = min(n0 + srow1, N - 1);
    const int soff = srow0 * 32 + sk;   // wave-uniform + lane*16B

    floatx4 acc[4][4] = {};

    for (int k0 = 0; k0 < K; k0 += 64) {
        __syncthreads();
        gload16(A  + (size_t)ar0 * K + k0 + sk,      &As[0][soff]);
        gload16(A  + (size_t)ar1 * K + k0 + sk,      &As[0][soff + 512]);
        gload16(A  + (size_t)ar0 * K + k0 + 32 + sk, &As[1][soff]);
        gload16(A  + (size_t)ar1 * K + k0 + 32 + sk, &As[1][soff + 512]);
        gload16(WT + (size_t)br0 * K + k0 + sk,      &Bs[0][soff]);
        gload16(WT + (size_t)br1 * K + k0 + sk,      &Bs[0][soff + 512]);
        gload16(WT + (size_t)br0 * K + k0 + 32 + sk, &Bs[1][soff]);
        gload16(WT + (size_t)br1 * K + k0 + 32 + sk, &Bs[1][soff + 512]);
        __syncthreads();

        #pragma unroll
        for (int kh = 0; kh < 2; ++kh) {
            bf16x8 a[4], b[4];
            #pragma unroll
            for (int ti = 0; ti < 4; ++ti)
                a[ti] = *(const bf16x8*)(&As[kh][(wm + ti * 16 + r) * 32 + quad * 8]);
            #pragma unroll
            for (int tj = 0; tj < 4; ++tj)
                b[tj] = *(const bf16x8*)(&Bs[kh][(wn + tj * 16 + r) * 32 + quad * 8]);
            #pragma unroll
            for (int ti = 0; ti < 4; ++ti)
                #pragma unroll
                for (int tj = 0; tj < 4; ++tj)
                    acc[ti][tj] = __builtin_amdgcn_mfma_f32_16x16x32_bf16(a[ti], b[tj], acc[ti][tj], 0, 0, 0);
        }
    }

    #pragma unroll
    for (int ti = 0; ti < 4; ++ti)
    #pragma unroll
    for (int tj = 0; tj < 4; ++tj) {
        int col = n0 + wn + tj * 16 + r;
        if (col >= N) continue;
        float bvv = bias ? bias[col] : 0.f;
        #pragma unroll
        for (int rr = 0; rr < 4; ++rr) {
            int row = m0 + wm + ti * 16 + quad * 4 + rr;
            if (row >= M) continue;
            float v = acc[ti][tj][rr] + bvv;
            if (resid) v += (float)resid[(size_t)row * N + col];
            if (relu)  v = v > 0.f ? v : 0.f;
            C[(size_t)row * N + col] = __float2bfloat16(v);
        }
    }
}

// ---------------------------------------------------------------------------
// cap2 GEMM specialized: C[1008,30522] = A[1008,768] @ WT[30522,768]^T + bias.
// XCD swizzle + register-direct f32 epilogue (r1-verified) + BK=64:
// 12 K-steps (was 24) -> half the vmcnt(0) drains & barrier syncs, 32 MFMA
// per barrier pair. (r6's dbuf-prefetch was neutral: the barrier drains the
// just-issued prefetch anyway; halving the DRAIN COUNT is what's left.)
// ---------------------------------------------------------------------------
__global__ __launch_bounds__(256) void gemm_cap2_kernel(
    const bf16* __restrict__ A, const bf16* __restrict__ WT,
    const float* __restrict__ bias, float* __restrict__ Cf,
    float2* __restrict__ part)
{
    __shared__ bf16 As[2][128 * 32];
    __shared__ bf16 Bs[2][128 * 32];
    const int id = blockIdx.x;
    const int xcd = id & 7, q = id >> 3;
    const int mt = q & 7, cg = q >> 3;
    const int nt = cg * 8 + xcd;
    if (nt >= C2NT) return;
    const int m0 = mt * 128, n0 = nt * 128;

    const int tid = threadIdx.x;
    const int lane = tid & 63, wave = tid >> 6;
    const int quad = lane >> 4, r = lane & 15;
    const int wm = (wave >> 1) * 64, wn = (wave & 1) * 64;
    const int srow0 = wave * 32 + (lane >> 2);
    const int srow1 = srow0 + 16;
    const int sk = (lane & 3) * 8;
    const int ar0 = min(m0 + srow0, C2M - 1), ar1 = min(m0 + srow1, C2M - 1);
    const int br0 = min(n0 + srow0, C2N - 1), br1 = min(n0 + srow1, C2N - 1);
    const int soff = srow0 * 32 + sk;

    floatx4 acc[4][4] = {};

    for (int k0 = 0; k0 < C2K; k0 += 64) {
        __syncthreads();
        gload16(A  + (size_t)ar0 * C2K + k0 + sk,      &As[0][soff]);
        gload16(A  + (size_t)ar1 * C2K + k0 + sk,      &As[0][soff + 512]);
        gload16(A  + (size_t)ar0 * C2K + k0 + 32 + sk, &As[1][soff]);
        gload16(A  + (size_t)ar1 * C2K + k0 + 32 + sk, &As[1][soff + 512]);
        gload16(WT + (size_t)br0 * C2K + k0 + sk,      &Bs[0][soff]);
        gload16(WT + (size_t)br1 * C2K + k0 + sk,      &Bs[0][soff + 512]);
        gload16(WT + (size_t)br0 * C2K + k0 + 32 + sk, &Bs[1][soff]);
        gload16(WT + (size_t)br1 * C2K + k0 + 32 + sk, &Bs[1][soff + 512]);
        __syncthreads();

        #pragma unroll
        for (int kh = 0; kh < 2; ++kh) {
            bf16x8 a[4], b[4];
            #pragma unroll
            for (int ti = 0; ti < 4; ++ti)
                a[ti] = *(const bf16x8*)(&As[kh][(wm + ti * 16 + r) * 32 + quad * 8]);
            #pragma unroll
            for (int tj = 0; tj < 4; ++tj)
                b[tj] = *(const bf16x8*)(&Bs[kh][(wn + tj * 16 + r) * 32 + quad * 8]);
            #pragma unroll
            for (int ti = 0; ti < 4; ++ti)
                #pragma unroll
                for (int tj = 0; tj < 4; ++tj)
                    acc[ti][tj] = __builtin_amdgcn_mfma_f32_16x16x32_bf16(a[ti], b[tj], acc[ti][tj], 0, 0, 0);
        }
    }

    // ---- register-direct epilogue (unchanged, r1-verified) ----
    float bv[4];
    bool cok[4];
    #pragma unroll
    for (int tj = 0; tj < 4; ++tj) {
        int col = n0 + wn + tj * 16 + r;
        cok[tj] = (col < C2N);
        bv[tj] = cok[tj] ? bias[col] : 0.f;
    }
    const int half = (wn >> 6);   // 0 or 1: which 64-col tile of this 128-tile

    #pragma unroll
    for (int ti = 0; ti < 4; ++ti) {
        #pragma unroll
        for (int rr = 0; rr < 4; ++rr) {
            const int rowg = m0 + wm + ti * 16 + quad * 4 + rr;
            const bool rok = (rowg < C2M);
            float v[4], vp[4];
            #pragma unroll
            for (int tj = 0; tj < 4; ++tj) {
                v[tj]  = acc[ti][tj][rr] + bv[tj];
                vp[tj] = cok[tj] ? v[tj] : -1e30f;
            }
            if (rok) {
                float* orow = Cf + (size_t)rowg * C2N;
                #pragma unroll
                for (int tj = 0; tj < 4; ++tj)
                    if (cok[tj]) orow[n0 + wn + tj * 16 + r] = v[tj];
            }
            float mx = fmaxf(fmaxf(vp[0], vp[1]), fmaxf(vp[2], vp[3]));
            #pragma unroll
            for (int o = 1; o < 16; o <<= 1) mx = fmaxf(mx, __shfl_xor(mx, o));
            float s = 0.f;
            #pragma unroll
            for (int tj = 0; tj < 4; ++tj)
                if (cok[tj]) s += __expf(v[tj] - mx);
            #pragma unroll
            for (int o = 1; o < 16; o <<= 1) s += __shfl_xor(s, o);
            if (r == 0 && rok)
                part[(size_t)rowg * C2H + nt * 2 + half] = make_float2(mx, s);
        }
    }
}

// ---------------------------------------------------------------------------
// Batched weight prep: transposes (f32 KxN -> bf16 NxK) + f32->bf16 copies.
// ---------------------------------------------------------------------------
struct PrepDesc { const float* src; bf16* dst; int K, N, tx, start, kind; };
struct PrepArgs { PrepDesc d[14]; };

__global__ __launch_bounds__(256) void prep_kernel(PrepArgs pa)
{
    const int bid = blockIdx.x;
    int op = 0;
    #pragma unroll
    for (int i = 1; i < 14; ++i) if (bid >= pa.d[i].start) op = i;
    const PrepDesc D = pa.d[op];
    const int lt = bid - D.start;
    const int tid = threadIdx.x;
    if (D.kind == 1) {   // contiguous f32 -> bf16 (sizes are exact *1024)
        int base = lt * 1024 + tid * 4;
        float4 v = *(const float4*)(D.src + base);
        bf16 o[4] = { __float2bfloat16(v.x), __float2bfloat16(v.y),
                      __float2bfloat16(v.z), __float2bfloat16(v.w) };
        *(uint2*)(D.dst + base) = *(uint2*)o;
    } else {             // 32x32 transpose tile (dims exact multiples of 32)
        __shared__ float tile[32][33];
        const int tx = tid & 31, ty = tid >> 5;
        const int n0 = (lt % D.tx) * 32, k0 = (lt / D.tx) * 32;
        #pragma unroll
        for (int yy = 0; yy < 32; yy += 8)
            tile[ty + yy][tx] = D.src[(size_t)(k0 + ty + yy) * D.N + n0 + tx];
        __syncthreads();
        #pragma unroll
        for (int yy = 0; yy < 32; yy += 8)
            D.dst[(size_t)(n0 + ty + yy) * D.K + k0 + tx] =
                __float2bfloat16(tile[tx][ty + yy]);
    }
}

// big standalone transpose for cap_w2 (runs late, overlays encoder arena)
__global__ __launch_bounds__(256) void transpose_kernel(
    const float* __restrict__ src, bf16* __restrict__ dst, int K, int N)
{
    __shared__ float tile[32][33];
    const int tx = threadIdx.x & 31, ty = threadIdx.x >> 5;
    const int n0 = blockIdx.x * 32, k0 = blockIdx.y * 32;
    #pragma unroll
    for (int yy = 0; yy < 32; yy += 8) {
        int k = k0 + ty + yy, n = n0 + tx;
        if (k < K && n < N) tile[ty + yy][tx] = src[(size_t)k * N + n];
    }
    __syncthreads();
    #pragma unroll
    for (int yy = 0; yy < 32; yy += 8) {
        int n = n0 + ty + yy, k = k0 + tx;
        if (n < N && k < K) dst[(size_t)n * K + k] = __float2bfloat16(tile[tx][ty + yy]);
    }
}

// ---------------------------------------------------------------------------
__global__ __launch_bounds__(256) void box_mean_kernel(
    const bf16* __restrict__ box, float* __restrict__ bm)
{
    const int b = blockIdx.x, tid = threadIdx.x;
    float s0 = 0.f, s1 = 0.f;
    for (int p = 0; p < NP; ++p) {
        const bf16* rw = box + (size_t)(b * NP + p) * ND;
        s0 += (float)rw[tid];
        s1 += (float)rw[tid + 256];
    }
    bm[b * ND + tid]       = s0 * (1.f / 64.f);
    bm[b * ND + tid + 256] = s1 * (1.f / 64.f);
}

__global__ __launch_bounds__(256) void build_x_kernel(
    const bf16* __restrict__ box, const bf16* __restrict__ txt,
    const float* __restrict__ bm, const int* __restrict__ tp,
    bf16* __restrict__ X)
{
    int idx = blockIdx.x * 256 + threadIdx.x;
    if (idx >= NROWS * ND) return;
    int d = idx & (ND - 1);
    int rs = idx >> 9;
    int row = rs % NS, seq = rs / NS;
    float v;
    if (seq < NB) {
        int b = seq;
        if (row < NP) v = (float)box[(size_t)(b * NP + row) * ND + d];
        else v = (float)txt[(size_t)(b * NT + row - NP) * ND + d] + bm[b * ND + d];
    } else {
        int s2 = seq - NB, b = s2 >> 1, k = s2 & 1;
        if (row < NP) v = (float)box[(size_t)(b * NP + row) * ND + d];
        else v = (float)txt[(size_t)(b * NT + row - NP) * ND + d]
               + (float)box[(size_t)(b * NP + tp[b * NK + k]) * ND + d];
    }
    X[idx] = __float2bfloat16(v);
}

// ---------------------------------------------------------------------------
__global__ __launch_bounds__(256) void attn_kernel(
    const bf16* __restrict__ QKV, bf16* __restrict__ Aout)
{
    const int blk = blockIdx.x;
    const int seq = blk / NS, i = blk % NS;
    const int tid = threadIdx.x;
    __shared__ float qs[ND];
    __shared__ float sc[128];
    __shared__ float red[64];

    const bf16* qrow = QKV + (size_t)(seq * NS + i) * 1536;
    qs[tid]       = (float)qrow[tid];
    qs[tid + 256] = (float)qrow[tid + 256];
    __syncthreads();

    int jmax = (seq < NB) ? NS : ((i < NP) ? NP : (i + 1));

    if (tid < NS) {
        const uint4* kp = (const uint4*)(QKV + (size_t)(seq * NS + tid) * 1536 + ND);
        float d = 0.f;
        #pragma unroll 4
        for (int c = 0; c < 64; ++c) {
            uint4 u = kp[c];
            int b0 = c * 8;
            d += qs[b0+0]*bflo(u.x) + qs[b0+1]*bfhi(u.x)
               + qs[b0+2]*bflo(u.y) + qs[b0+3]*bfhi(u.y)
               + qs[b0+4]*bflo(u.z) + qs[b0+5]*bfhi(u.z)
               + qs[b0+6]*bflo(u.w) + qs[b0+7]*bfhi(u.w);
        }
        sc[tid] = (tid < jmax) ? d * 0.04419417382415922f : -1e9f;
    } else if (tid == NS) {
        sc[NS] = -1e9f;
    }
    __syncthreads();

    if (tid < 64) red[tid] = fmaxf(sc[tid], sc[tid + 64]);
    __syncthreads();
    for (int s = 32; s > 0; s >>= 1) {
        if (tid < s) red[tid] = fmaxf(red[tid], red[tid + s]);
        __syncthreads();
    }
    float m = red[0];
    __syncthreads();

    if (tid < 128) sc[tid] = __expf(sc[tid] - m);
    __syncthreads();
    if (tid < 64) red[tid] = sc[tid] + sc[tid + 64];
    __syncthreads();
    for (int s = 32; s > 0; s >>= 1) {
        if (tid < s) red[tid] += red[tid + s];
        __syncthreads();
    }
    float inv = 1.f / red[0];

    const unsigned* vp = (const unsigned*)(QKV + (size_t)(seq * NS) * 1536 + 1024);
    float a0 = 0.f, a1 = 0.f;
    for (int j = 0; j < jmax; ++j) {
        float p = sc[j];
        unsigned u = vp[(size_t)j * 768 + tid];
        a0 += p * bflo(u);
        a1 += p * bfhi(u);
    }
    bf16* orow = Aout + (size_t)(seq * NS + i) * ND;
    orow[2 * tid]     = __float2bfloat16(a0 * inv);
    orow[2 * tid + 1] = __float2bfloat16(a1 * inv);
}

// ---------------------------------------------------------------------------
__global__ __launch_bounds__(256) void ln_kernel(
    const bf16* __restrict__ Y, const float* __restrict__ g,
    const float* __restrict__ b, bf16* __restrict__ X)
{
    const int row = blockIdx.x, tid = threadIdx.x;
    const bf16* y = Y + (size_t)row * ND;
    float v0 = (float)y[tid], v1 = (float)y[tid + 256];
    __shared__ float rs[256], rq[256];
    rs[tid] = v0 + v1;
    rq[tid] = v0 * v0 + v1 * v1;
    __syncthreads();
    for (int s = 128; s > 0; s >>= 1) {
        if (tid < s) { rs[tid] += rs[tid + s]; rq[tid] += rq[tid + s]; }
        __syncthreads();
    }
    float mean = rs[0] * (1.f / ND);
    float var = rq[0] * (1.f / ND) - mean * mean;
    float rstd = rsqrtf(var + 1e-5f);
    bf16* x = X + (size_t)row * ND;
    x[tid]       = __float2bfloat16((v0 - mean) * rstd * g[tid] + b[tid]);
    x[tid + 256] = __float2bfloat16((v1 - mean) * rstd * g[tid + 256] + b[tid + 256]);
}

// ---------------------------------------------------------------------------
__global__ __launch_bounds__(256) void match_head_kernel(
    const bf16* __restrict__ X, const float* __restrict__ w1, const float* __restrict__ b1,
    const float* __restrict__ w2, const float* __restrict__ b2,
    float* __restrict__ msf, float* __restrict__ out)
{
    const int blk = blockIdx.x;
    const int b = blk >> 6, p = blk & 63;
    const int tid = threadIdx.x;
    const bf16* x = X + (size_t)(b * NS + p) * ND;
    __shared__ float xs[ND];
    __shared__ float red[256];
    xs[tid] = (float)x[tid]; xs[tid + 256] = (float)x[tid + 256];
    __syncthreads();
    float h = b1[tid];
    for (int d = 0; d < ND; ++d) h += xs[d] * w1[d * 256 + tid];
    red[tid] = h * w2[tid];
    __syncthreads();
    for (int s = 128; s > 0; s >>= 1) {
        if (tid < s) red[tid] += red[tid + s];
        __syncthreads();
    }
    if (tid == 0) {
        float scv = red[0] + b2[0];
        msf[blk] = scv;
        out[OUT_MS + blk] = scv;
    }
}

__global__ __launch_bounds__(256) void cls_head_kernel(
    const bf16* __restrict__ X, const float* __restrict__ w1, const float* __restrict__ b1,
    const float* __restrict__ w2, const float* __restrict__ b2,
    float* __restrict__ csf, float* __restrict__ out)
{
    const int b = blockIdx.x, tid = threadIdx.x;
    const bf16* x = X + (size_t)(b * NS + NP) * ND;
    __shared__ float xs[ND];
    __shared__ float hs[256];
    xs[tid] = (float)x[tid]; xs[tid + 256] = (float)x[tid + 256];
    __syncthreads();
    float h = b1[tid];
    for (int d = 0; d < ND; ++d) h += xs[d] * w1[d * 256 + tid];
    hs[tid] = h;
    __syncthreads();
    if (tid < NNC) {
        float scv = b2[tid];
        for (int c = 0; c < 256; ++c) scv += hs[c] * w2[c * NNC + tid];
        csf[b * NNC + tid] = scv;
        out[OUT_CS + b * NNC + tid] = scv;
    }
}

__global__ void small_loss_kernel(
    const float* __restrict__ msf, const float* __restrict__ csf,
    const int* __restrict__ tp, const int* __restrict__ tc, float* __restrict__ out)
{
    const int tid = threadIdx.x;
    float mloss = 0.f;
    for (int b = 0; b < NB; ++b) {
        float s = msf[b * NP + tid];
        float m = s;
        for (int o = 32; o > 0; o >>= 1) m = fmaxf(m, __shfl_xor(m, o));
        float e = __expf(s - m);
        float sum = e;
        for (int o = 32; o > 0; o >>= 1) sum += __shfl_xor(sum, o);
        float lse = m + __logf(sum);
        float w = (tid == tp[2 * b] || tid == tp[2 * b + 1]) ? 0.5f : 0.f;
        float c = w * (lse - s);
        for (int o = 32; o > 0; o >>= 1) c += __shfl_xor(c, o);
        mloss += c;
    }
    float closs = 0.f;
    for (int b = 0; b < NB; ++b) {
        float s = (tid < NNC) ? csf[b * NNC + tid] : -1e30f;
        float m = s;
        for (int o = 32; o > 0; o >>= 1) m = fmaxf(m, __shfl_xor(m, o));
        float e = (tid < NNC) ? __expf(s - m) : 0.f;
        float sum = e;
        for (int o = 32; o > 0; o >>= 1) sum += __shfl_xor(sum, o);
        if (tid == 0) closs += (m + __logf(sum)) - csf[b * NNC + tc[b]];
    }
    if (tid == 0) {
        out[OUT_MLOSS] = mloss * (1.f / NB);
        out[OUT_CLOSS] = closs * (1.f / NB);
    }
}

__global__ __launch_bounds__(256) void gather_xc_kernel(
    const bf16* __restrict__ X, bf16* __restrict__ Xc)
{
    int idx = blockIdx.x * 256 + threadIdx.x;
    if (idx >= 1008 * ND) return;
    int d = idx & (ND - 1);
    int r = idx >> 9;
    int seq = NB + r / NT, t = r % NT;
    Xc[idx] = X[(size_t)(seq * NS + NP + t) * ND + d];
}

// combine per-tile softmax partials -> dc loss (two passes over L2-resident part)
__global__ void dc_combine_kernel(
    const float2* __restrict__ part, const float* __restrict__ scores,
    const int* __restrict__ twid, float* __restrict__ accf)
{
    const int rr = blockIdx.x, t = threadIdx.x;
    const float2* pr = part + (size_t)rr * C2H;
    float mx = -1e30f;
    for (int i = t; i < C2H; i += 64) mx = fmaxf(mx, pr[i].x);
    for (int o = 1; o < 64; o <<= 1) mx = fmaxf(mx, __shfl_xor(mx, o));
    float s = 0.f;
    for (int i = t; i < C2H; i += 64) {
        float2 p = pr[i];
        s += p.y * __expf(p.x - mx);
    }
    for (int o = 1; o < 64; o <<= 1) s += __shfl_xor(s, o);
    if (t == 0) {
        int b = rr / 126, rem = rr % 126, tok = rem % 63;
        int wid = twid[b * 64 + 1 + tok];
        float lse = mx + __logf(s);
        atomicAdd(accf, (lse - scores[(size_t)rr * C2N + wid]) * (1.f / 504.f));
    }
}

__global__ void init_kernel(float* __restrict__ acc)
{
    if (threadIdx.x < 16) acc[threadIdx.x] = 0.f;
}

__global__ void finalize_kernel(const float* __restrict__ acc, float* __restrict__ out)
{
    out[OUT_DCLOSS] = acc[0];
}

// ---------------------------------------------------------------------------
extern "C" void kernel_launch(void* const* d_in, const int* in_sizes, int n_in,
                              void* d_out, int out_size, void* d_ws, size_t ws_size,
                              hipStream_t stream)
{
    const float* instances = (const float*)d_in[0];
    const float* text_emb  = (const float*)d_in[1];
    const int*   tp        = (const int*)d_in[2];
    const int*   twid      = (const int*)d_in[3];
    const int*   tcls      = (const int*)d_in[4];
    const float* Wi1 = (const float*)d_in[5];  const float* bi1 = (const float*)d_in[6];
    const float* Wi2 = (const float*)d_in[7];  const float* bi2 = (const float*)d_in[8];
    const float* Ww  = (const float*)d_in[9];  const float* bw  = (const float*)d_in[10];
    const float* qkv_w = (const float*)d_in[11]; const float* qkv_b = (const float*)d_in[12];
    const float* out_w = (const float*)d_in[13]; const float* out_b = (const float*)d_in[14];
    const float* ln1_g = (const float*)d_in[15]; const float* ln1_b = (const float*)d_in[16];
    const float* ff1_w = (const float*)d_in[17]; const float* ff1_b = (const float*)d_in[18];
    const float* ff2_w = (const float*)d_in[19]; const float* ff2_b = (const float*)d_in[20];
    const float* ln2_g = (const float*)d_in[21]; const float* ln2_b = (const float*)d_in[22];
    const float* grd_w1 = (const float*)d_in[23]; const float* grd_b1 = (const float*)d_in[24];
    const float* grd_w2 = (const float*)d_in[25]; const float* grd_b2 = (const float*)d_in[26];
    const float* cls_w1 = (const float*)d_in[27]; const float* cls_b1 = (const float*)d_in[28];
    const float* cls_w2 = (const float*)d_in[29]; const float* cls_b2 = (const float*)d_in[30];
    const float* cap_w1 = (const float*)d_in[31]; const float* cap_b1 = (const float*)d_in[32];
    const float* cap_w2 = (const float*)d_in[33]; const float* cap_b2 = (const float*)d_in[34];

    float* out = (float*)d_out;

    // ---- workspace layout (~60 MB peak; cap_w2^T overlays encoder arena) ----
    char* base = (char*)d_ws;
    size_t o = 0;
    auto nxtb = [&](size_t bytes) -> char* {
        char* p = base + o; o += (bytes + 255) & ~(size_t)255; return p;
    };
    float*  bm   = (float*)nxtb(NB * ND * 4);
    float*  msf  = (float*)nxtb(512 * 4);
    float*  csf  = (float*)nxtb(144 * 4);
    float*  accf = (float*)nxtb(64);
    float2* part = (float2*)nxtb((size_t)C2M * C2H * 8);
    bf16* wt_cap1 = (bf16*)nxtb((size_t)768 * 512 * 2);
    bf16* Xc    = (bf16*)nxtb((size_t)1008 * 512 * 2);
    bf16* C1    = (bf16*)nxtb((size_t)1008 * 768 * 2);
    size_t arena0 = o;
    bf16* wt_wi1  = (bf16*)nxtb((size_t)1024 * 1536 * 2);
    bf16* wt_wi2  = (bf16*)nxtb((size_t)512 * 1024 * 2);
    bf16* wt_ww   = (bf16*)nxtb((size_t)512 * 768 * 2);
    bf16* wt_qkv  = (bf16*)nxtb((size_t)2 * 1536 * 512 * 2);
    bf16* wt_out  = (bf16*)nxtb((size_t)2 * 512 * 512 * 2);
    bf16* wt_ff1  = (bf16*)nxtb((size_t)2 * 2048 * 512 * 2);
    bf16* wt_ff2  = (bf16*)nxtb((size_t)2 * 512 * 2048 * 2);
    bf16* inst_b  = (bf16*)nxtb((size_t)512 * 1536 * 2);
    bf16* txt_b   = (bf16*)nxtb((size_t)504 * 768 * 2);
    bf16* box_h   = (bf16*)nxtb((size_t)512 * 1024 * 2);
    bf16* box     = (bf16*)nxtb((size_t)512 * 512 * 2);
    bf16* txt     = (bf16*)nxtb((size_t)504 * 512 * 2);
    bf16* X       = (bf16*)nxtb((size_t)NROWS * ND * 2);
    bf16* QKV     = (bf16*)nxtb((size_t)NROWS * 1536 * 2);
    bf16* Aout    = (bf16*)nxtb((size_t)NROWS * ND * 2);
    bf16* Ybuf    = (bf16*)nxtb((size_t)NROWS * ND * 2);
    bf16* Hbuf    = (bf16*)nxtb((size_t)NROWS * NDFF * 2);
    bf16* wt_cap2 = (bf16*)(base + arena0);  // 46.9 MB, overlays arena late

    const dim3 tb(256);

    init_kernel<<<1, 64, 0, stream>>>(accf);

    // ---- batched weight prep (12 transposes + 2 copies, one launch) ----
    PrepArgs pa;
    int cur = 0, pi = 0;
    auto addT = [&](const float* s, bf16* d, int K, int N) {
        pa.d[pi] = PrepDesc{ s, d, K, N, N / 32, cur, 0 };
        cur += (N / 32) * (K / 32); pi++;
    };
    auto addC = [&](const float* s, bf16* d, int elems) {
        pa.d[pi] = PrepDesc{ s, d, 0, 0, 0, cur, 1 };
        cur += elems / 1024; pi++;
    };
    addT(Wi1, wt_wi1, 1536, 1024);
    addT(Wi2, wt_wi2, 1024, 512);
    addT(Ww,  wt_ww,  768,  512);
    for (int l = 0; l < 2; ++l) {
        addT(qkv_w + (size_t)l * 512 * 1536, wt_qkv + (size_t)l * 1536 * 512, 512, 1536);
        addT(out_w + (size_t)l * 512 * 512,  wt_out + (size_t)l * 512 * 512,  512, 512);
        addT(ff1_w + (size_t)l * 512 * 2048, wt_ff1 + (size_t)l * 2048 * 512, 512, 2048);
        addT(ff2_w + (size_t)l * 2048 * 512, wt_ff2 + (size_t)l * 512 * 2048, 2048, 512);
    }
    addT(cap_w1, wt_cap1, 512, 768);
    addC(instances, inst_b, 512 * 1536);
    addC(text_emb,  txt_b,  504 * 768);
    prep_kernel<<<cur, tb, 0, stream>>>(pa);

    auto G64 = [&](const bf16* A, const bf16* WT, const float* bias, const bf16* resid,
                   bf16* C, int M, int N, int K, int relu) {
        dim3 g((M + 63) / 64, (N + 63) / 64);
        gemm_kernel<<<g, tb, 0, stream>>>(A, WT, bias, resid, C, M, N, K, relu);
    };
    auto G128 = [&](const bf16* A, const bf16* WT, const float* bias, const bf16* resid,
                    bf16* C, int M, int N, int K, int relu) {
        dim3 g((M + 127) / 128, (N + 127) / 128);
        gemm128_kernel<<<g, tb, 0, stream>>>(A, WT, bias, resid, C, M, N, K, relu);
    };

    // box/text embeddings
    G64(inst_b, wt_wi1, bi1, nullptr, box_h, 512, 1024, 1536, 0);
    G64(box_h,  wt_wi2, bi2, nullptr, box,   512, 512,  1024, 0);
    G64(txt_b,  wt_ww,  bw,  nullptr, txt,   504, 512,  768,  0);

    box_mean_kernel<<<NB, tb, 0, stream>>>(box, bm);
    build_x_kernel<<<(NROWS * ND) / 256, tb, 0, stream>>>(box, txt, bm, tp, X);

    // encoder, 2 layers
    for (int l = 0; l < 2; ++l) {
        G128(X, wt_qkv + (size_t)l * 1536 * 512, qkv_b + l * 1536, nullptr, QKV,
             NROWS, 1536, 512, 0);
        attn_kernel<<<NROWS, tb, 0, stream>>>(QKV, Aout);
        G64(Aout, wt_out + (size_t)l * 512 * 512, out_b + l * 512, X, Ybuf,
            NROWS, 512, 512, 0);
        ln_kernel<<<NROWS, tb, 0, stream>>>(Ybuf, ln1_g + l * 512, ln1_b + l * 512, X);
        G128(X, wt_ff1 + (size_t)l * 2048 * 512, ff1_b + l * 2048, nullptr, Hbuf,
             NROWS, 2048, 512, 1);
        G64(Hbuf, wt_ff2 + (size_t)l * 512 * 2048, ff2_b + l * 512, X, Ybuf,
            NROWS, 512, 2048, 0);
        ln_kernel<<<NROWS, tb, 0, stream>>>(Ybuf, ln2_g + l * 512, ln2_b + l * 512, X);
    }

    // heads + small losses
    match_head_kernel<<<512, tb, 0, stream>>>(X, grd_w1, grd_b1, grd_w2, grd_b2, msf, out);
    cls_head_kernel<<<NB, tb, 0, stream>>>(X, cls_w1, cls_b1, cls_w2, cls_b2, csf, out);
    small_loss_kernel<<<1, 64, 0, stream>>>(msf, csf, tp, tcls, out);

    gather_xc_kernel<<<(1008 * ND) / 256, tb, 0, stream>>>(X, Xc);
    G64(Xc, wt_cap1, cap_b1, nullptr, C1, 1008, 768, 512, 0);

    // caption vocab projection (f32 straight into d_out, fused softmax partials)
    {
        dim3 g((C2N + 31) / 32, (C2K + 31) / 32);
        transpose_kernel<<<g, tb, 0, stream>>>(cap_w2, wt_cap2, C2K, C2N);
    }
    gemm_cap2_kernel<<<8 * 8 * 30, tb, 0, stream>>>(C1, wt_cap2, cap_b2,
                                                    out + OUT_DC, part);

    dc_combine_kernel<<<1008, 64, 0, stream>>>(part, out + OUT_DC, twid, accf);
    finalize_kernel<<<1, 1, 0, stream>>>(accf, out);

    (void)in_sizes; (void)n_in; (void)out_size; (void)ws_size;
}